// Round 6
// baseline (372.485 us; speedup 1.0000x reference)
//
#include <hip/hip_runtime.h>
#include <stdint.h>

#define S_LEN 4096
#define SCALE_LOG2E 0.18033688011112042f   // (1/sqrt(64)) * log2(e), folded into Q

typedef __attribute__((ext_vector_type(8))) short bf16x8;
typedef __attribute__((ext_vector_type(4))) float f32x4;

#if __has_builtin(__builtin_amdgcn_exp2f)
#define EXP2(x) __builtin_amdgcn_exp2f(x)
#else
#define EXP2(x) exp2f(x)
#endif

__device__ __forceinline__ unsigned pk2(float a, float b) {
    // round-half-up bf16 pair pack: +0x8000 then take high halves via v_perm
    unsigned ua = __builtin_bit_cast(unsigned, a) + 0x8000u;
    unsigned ub = __builtin_bit_cast(unsigned, b) + 0x8000u;
    return __builtin_amdgcn_perm(ub, ua, 0x07060302u);
}

__device__ __forceinline__ f32x4 mfma16(bf16x8 a, bf16x8 b, f32x4 c) {
    return __builtin_amdgcn_mfma_f32_16x16x32_bf16(a, b, c, 0, 0, 0);
}

// ------------- mask packing: bool(any encoding) -> bitfield, [kt][q] layout --
__global__ void pack_mask_kernel(const unsigned* __restrict__ m32,
                                 unsigned long long* __restrict__ out) {
    const int lane = threadIdx.x & 63;
    const int w = threadIdx.x >> 6;
    unsigned pv = m32[lane];
    bool okw = (pv == 0u) || (pv == 1u) || (pv == 0x3F800000u);
    const bool is_word = (__ballot(okw) == ~0ull);
    const long long wbase = ((long long)blockIdx.x * 4 + w) * 4;   // u64 words (q*64+kt)
    const unsigned char* m8 = (const unsigned char*)m32;
#pragma unroll
    for (int it = 0; it < 4; ++it) {
        const long long word = wbase + it;
        long long e = word * 64 + lane;
        bool bit = is_word ? (m32[e] != 0u) : (m8[e] != 0);
        unsigned long long bal = __ballot(bit);
        if (lane == 0) {
            long long q = word >> 6, kt = word & 63;
            out[kt * S_LEN + q] = bal;   // transposed: coalesced reads in attn
        }
    }
}

// ---------------- staging: global fp32 -> regs (packed bf16), 256 threads ----
__device__ __forceinline__ void pf_load(const float* __restrict__ K,
                                        const float* __restrict__ V,
                                        int bh, int k0, int t,
                                        unsigned* kb, unsigned* vb) {
    const int r = t >> 2, h = t & 3;
    const float* kp = K + (((size_t)(bh * S_LEN + k0 + r)) << 6) + h * 16;
#pragma unroll
    for (int cc = 0; cc < 2; ++cc) {
        float4 f0 = ((const float4*)kp)[cc * 2];
        float4 f1 = ((const float4*)kp)[cc * 2 + 1];
        kb[cc * 4 + 0] = pk2(f0.x, f0.y);
        kb[cc * 4 + 1] = pk2(f0.z, f0.w);
        kb[cc * 4 + 2] = pk2(f1.x, f1.y);
        kb[cc * 4 + 3] = pk2(f1.z, f1.w);
    }
    const int d = t & 63, g = t >> 6;
    const float* vp = V + (((size_t)(bh * S_LEN + k0 + g * 16)) << 6) + d;
#pragma unroll
    for (int c8 = 0; c8 < 2; ++c8) {
        float f[8];
#pragma unroll
        for (int i = 0; i < 8; ++i) f[i] = vp[(c8 * 8 + i) * 64];
        vb[c8 * 4 + 0] = pk2(f[0], f[1]);
        vb[c8 * 4 + 1] = pk2(f[2], f[3]);
        vb[c8 * 4 + 2] = pk2(f[4], f[5]);
        vb[c8 * 4 + 3] = pk2(f[6], f[7]);
    }
}

__device__ __forceinline__ void pf_store(int t, const unsigned* kb, const unsigned* vb,
                                         unsigned short* lk, unsigned short* lv) {
    const int r = t >> 2, h = t & 3;
#pragma unroll
    for (int cc = 0; cc < 2; ++cc) {
        int c = h * 2 + cc;
        uint4 st = {kb[cc * 4 + 0], kb[cc * 4 + 1], kb[cc * 4 + 2], kb[cc * 4 + 3]};
        *(uint4*)&lk[r * 64 + ((c ^ (r & 7)) << 3)] = st;
    }
    const int d = t & 63, g = t >> 6;
#pragma unroll
    for (int c8 = 0; c8 < 2; ++c8) {
        int c = g * 2 + c8;
        uint4 st = {vb[c8 * 4 + 0], vb[c8 * 4 + 1], vb[c8 * 4 + 2], vb[c8 * 4 + 3]};
        *(uint4*)&lv[d * 64 + ((c ^ (d & 7)) << 3)] = st;
    }
}

// -------- one 64-key tile, processed as two 32-key halves ---------------------
// Per half: S^T = K·Q^T (8 mfma), softmax -> lp (per-wave 2 KB), O^T += V^T·P^T
// (8 mfma) + row-sum via ones-MFMA (2 mfma). No barrier: lp is wave-private,
// LDS ops are in-order per wave.
__device__ __forceinline__ void compute_tile(
    int n16, int quad,
    const unsigned long long (&mrow)[2],
    const unsigned short* lk, const unsigned short* lv, unsigned short* lp,
    const bf16x8 (&aq)[2][2], const bf16x8 ones,
    f32x4 (&oacc)[4][2], f32x4 (&lacc)[2]) {
#pragma unroll
    for (int mth = 0; mth < 2; ++mth) {
        f32x4 sac[2][2];
        const f32x4 z = {0.f, 0.f, 0.f, 0.f};
#pragma unroll
        for (int mi = 0; mi < 2; ++mi)
#pragma unroll
            for (int nt = 0; nt < 2; ++nt) sac[mi][nt] = z;
#pragma unroll
        for (int kd = 0; kd < 2; ++kd) {
#pragma unroll
            for (int mi = 0; mi < 2; ++mi) {
                int row = (mth * 2 + mi) * 16 + n16;
                bf16x8 ak = *(const bf16x8*)&lk[row * 64 + (((kd * 4 + quad) ^ (row & 7)) << 3)];
#pragma unroll
                for (int nt = 0; nt < 2; ++nt)
                    sac[mi][nt] = mfma16(ak, aq[nt][kd], sac[mi][nt]);
            }
        }
        // softmax numerators -> lp rows [q:32][k'_local:32] (64 B rows, swizzled)
#pragma unroll
        for (int mi = 0; mi < 2; ++mi) {
#pragma unroll
            for (int nt = 0; nt < 2; ++nt) {
                const int mt = mth * 2 + mi;
                unsigned bits4 = (unsigned)(mrow[nt] >> (mt * 16 + quad * 4)) & 0xFu;
                float p[4];
#pragma unroll
                for (int reg = 0; reg < 4; ++reg) {
                    float e = EXP2(sac[mi][nt][reg]);
                    p[reg] = ((bits4 >> reg) & 1u) ? e : 0.0f;
                }
                uint2 pr = {pk2(p[0], p[1]), pk2(p[2], p[3])};
                const int r = nt * 16 + n16;
                const int c = (mi * 2 + (quad >> 1)) ^ (n16 & 3);
                *(uint2*)((char*)lp + r * 64 + c * 16 + (quad & 1) * 8) = pr;
            }
        }
        // PV half: k' chunk = mth
        bf16x8 av[4];
#pragma unroll
        for (int md = 0; md < 4; ++md) {
            int dr = md * 16 + n16;
            av[md] = *(const bf16x8*)&lv[dr * 64 + (((mth * 4 + quad) ^ (dr & 7)) << 3)];
        }
#pragma unroll
        for (int nt = 0; nt < 2; ++nt) {
            const int r = nt * 16 + n16;
            const int c = quad ^ (n16 & 3);
            bf16x8 pb = *(const bf16x8*)((const char*)lp + r * 64 + c * 16);
            lacc[nt] = mfma16(ones, pb, lacc[nt]);
#pragma unroll
            for (int md = 0; md < 4; ++md)
                oacc[md][nt] = mfma16(av[md], pb, oacc[md][nt]);
        }
    }
}

__device__ __forceinline__ void load_q_frags(const float* __restrict__ Q, int bh, int q0w,
                                             int n16, int quad, bf16x8 (&aq)[2][2]) {
#pragma unroll
    for (int nt = 0; nt < 2; ++nt) {
        const float* qp = Q + ((size_t)(bh * S_LEN + q0w + nt * 16 + n16) << 6);
#pragma unroll
        for (int kd = 0; kd < 2; ++kd) {
            float4 f0 = *(const float4*)(qp + kd * 32 + quad * 8);
            float4 f1 = *(const float4*)(qp + kd * 32 + quad * 8 + 4);
            uint4 u = {pk2(f0.x * SCALE_LOG2E, f0.y * SCALE_LOG2E),
                       pk2(f0.z * SCALE_LOG2E, f0.w * SCALE_LOG2E),
                       pk2(f1.x * SCALE_LOG2E, f1.y * SCALE_LOG2E),
                       pk2(f1.z * SCALE_LOG2E, f1.w * SCALE_LOG2E)};
            aq[nt][kd] = __builtin_bit_cast(bf16x8, u);
        }
    }
}

__device__ __forceinline__ bf16x8 make_ones() {
    const short o = (short)0x3F80;   // bf16 1.0
    bf16x8 v = {o, o, o, o, o, o, o, o};
    return v;
}

// ============ K-split partial kernel: blockIdx.z = key half, packed mask =====
__global__ __launch_bounds__(256, 3) void attn_partial(
    const float* __restrict__ Q, const float* __restrict__ K, const float* __restrict__ V,
    const unsigned long long* __restrict__ pm,
    float* __restrict__ Opart, float* __restrict__ Lpart) {
    __shared__ __align__(16) unsigned short lk[2][64 * 64];
    __shared__ __align__(16) unsigned short lv[2][64 * 64];
    __shared__ __align__(16) unsigned short lpbuf[4][32 * 32];
    const int tid = threadIdx.x;
    const int lane = tid & 63;
    const int w = tid >> 6;
    const int n16 = lane & 15;
    const int quad = lane >> 4;
    const int bh = blockIdx.y;
    const int half = blockIdx.z;
    const int q0w = blockIdx.x * 128 + w * 32;
    const int kbase = half * 2048;
    unsigned short* lp = lpbuf[w];

    bf16x8 aq[2][2];
    load_q_frags(Q, bh, q0w, n16, quad, aq);
    const bf16x8 ones = make_ones();

    f32x4 oacc[4][2];
    f32x4 lacc[2];
    const f32x4 z = {0.f, 0.f, 0.f, 0.f};
#pragma unroll
    for (int md = 0; md < 4; ++md)
#pragma unroll
        for (int nt = 0; nt < 2; ++nt) oacc[md][nt] = z;
    lacc[0] = z; lacc[1] = z;

    unsigned kb[8], vb[8];
    pf_load(K, V, bh, kbase, tid, kb, vb);
    pf_store(tid, kb, vb, lk[0], lv[0]);
    unsigned long long mrow_cur[2], mrow_nxt[2];
#pragma unroll
    for (int nt = 0; nt < 2; ++nt)
        mrow_cur[nt] = pm[(size_t)(half * 32) * S_LEN + q0w + nt * 16 + n16];

    for (int ktl = 0; ktl < 32; ++ktl) {
        const int cur = ktl & 1;
        const int ktn = (ktl + 1) & 31;
        __syncthreads();
        pf_load(K, V, bh, kbase + ktn * 64, tid, kb, vb);
#pragma unroll
        for (int nt = 0; nt < 2; ++nt)
            mrow_nxt[nt] = pm[(size_t)(half * 32 + ktn) * S_LEN + q0w + nt * 16 + n16];
        compute_tile(n16, quad, mrow_cur, lk[cur], lv[cur], lp, aq, ones, oacc, lacc);
        pf_store(tid, kb, vb, lk[cur ^ 1], lv[cur ^ 1]);
        mrow_cur[0] = mrow_nxt[0];
        mrow_cur[1] = mrow_nxt[1];
    }

    // store raw partial O^T + row sums (lacc already full-width via ones-MFMA)
#pragma unroll
    for (int nt = 0; nt < 2; ++nt) {
        int q = q0w + nt * 16 + n16;
        if (quad == 0) Lpart[((size_t)(half * 16 + bh) << 12) + q] = lacc[nt][0];
#pragma unroll
        for (int md = 0; md < 4; ++md) {
            float4 o;
            o.x = oacc[md][nt][0];
            o.y = oacc[md][nt][1];
            o.z = oacc[md][nt][2];
            o.w = oacc[md][nt][3];
            *(float4*)(Opart + (((size_t)(half * 16 + bh) << 12) + q) * 64 +
                       md * 16 + quad * 4) = o;
        }
    }
}

// ============ combine: O = (O0 + O1) / (l0 + l1) =============================
__global__ __launch_bounds__(256) void combine_kernel(
    const float* __restrict__ Opart, const float* __restrict__ Lpart,
    float* __restrict__ O) {
    const int row = blockIdx.x * 16 + (threadIdx.x >> 4);      // bh*4096+q
    const int d4 = (threadIdx.x & 15) * 4;
    const float* p0 = Opart + (size_t)row * 64 + d4;
    const float* p1 = p0 + (size_t)16 * S_LEN * 64;
    float4 a = *(const float4*)p0;
    float4 b = *(const float4*)p1;
    float l = Lpart[row] + Lpart[16 * S_LEN + row];
    float r = (l > 0.f) ? (1.0f / l) : 0.0f;
    float4 o;
    o.x = (a.x + b.x) * r;
    o.y = (a.y + b.y) * r;
    o.z = (a.z + b.z) * r;
    o.w = (a.w + b.w) * r;
    *(float4*)(O + (size_t)row * 64 + d4) = o;
}

// ============ fallback: single kernel, full key range, raw mask ==============
__global__ __launch_bounds__(256, 3) void attn_kernel(
    const float* __restrict__ Q, const float* __restrict__ K, const float* __restrict__ V,
    const unsigned* __restrict__ rawmask, float* __restrict__ O) {
    __shared__ __align__(16) unsigned short lk[2][64 * 64];
    __shared__ __align__(16) unsigned short lv[2][64 * 64];
    __shared__ __align__(16) unsigned short lpbuf[4][32 * 32];
    const int tid = threadIdx.x;
    const int lane = tid & 63;
    const int w = tid >> 6;
    const int n16 = lane & 15;
    const int quad = lane >> 4;
    const int bh = blockIdx.y;
    const int q0w = blockIdx.x * 128 + w * 32;
    unsigned short* lp = lpbuf[w];

    unsigned v = rawmask[lane];
    bool okw = (v == 0u) || (v == 1u) || (v == 0x3F800000u);
    const int mask_is_word = (__ballot(okw) == ~0ull) ? 1 : 0;

    bf16x8 aq[2][2];
    load_q_frags(Q, bh, q0w, n16, quad, aq);
    const bf16x8 ones = make_ones();

    f32x4 oacc[4][2];
    f32x4 lacc[2];
    const f32x4 z = {0.f, 0.f, 0.f, 0.f};
#pragma unroll
    for (int md = 0; md < 4; ++md)
#pragma unroll
        for (int nt = 0; nt < 2; ++nt) oacc[md][nt] = z;
    lacc[0] = z; lacc[1] = z;

    unsigned kb[8], vb[8];
    pf_load(K, V, bh, 0, tid, kb, vb);
    pf_store(tid, kb, vb, lk[0], lv[0]);

    for (int kt = 0; kt < 64; ++kt) {
        const int cur = kt & 1;
        const int ktn = (kt + 1) & 63;
        __syncthreads();
        pf_load(K, V, bh, ktn * 64, tid, kb, vb);
        // build mask bits for this tile from raw mask (fallback path)
        unsigned long long mrow_cur[2];
#pragma unroll
        for (int nt = 0; nt < 2; ++nt) {
            unsigned long long mm = 0;
            size_t base = (size_t)(q0w + nt * 16 + n16) * S_LEN + kt * 64;
#pragma unroll
            for (int b = 0; b < 4; ++b) {
                int pos = b * 16 + quad * 4;
#pragma unroll
                for (int reg = 0; reg < 4; ++reg) {
                    bool bit = mask_is_word ? (rawmask[base + pos + reg] != 0u)
                                            : (((const unsigned char*)rawmask)[base + pos + reg] != 0);
                    if (bit) mm |= 1ull << (pos + reg);
                }
            }
            mrow_cur[nt] = mm;
        }
        compute_tile(n16, quad, mrow_cur, lk[cur], lv[cur], lp, aq, ones, oacc, lacc);
        pf_store(tid, kb, vb, lk[cur ^ 1], lv[cur ^ 1]);
    }

    float rcpl[2];
#pragma unroll
    for (int nt = 0; nt < 2; ++nt) {
        float l = lacc[nt][0];
        rcpl[nt] = (l > 0.f) ? (1.0f / l) : 0.0f;
    }
#pragma unroll
    for (int md = 0; md < 4; ++md)
#pragma unroll
        for (int nt = 0; nt < 2; ++nt) {
            int q = q0w + nt * 16 + n16;
            float4 o;
            o.x = oacc[md][nt][0] * rcpl[nt];
            o.y = oacc[md][nt][1] * rcpl[nt];
            o.z = oacc[md][nt][2] * rcpl[nt];
            o.w = oacc[md][nt][3] * rcpl[nt];
            *(float4*)(O + ((size_t)(bh * S_LEN + q) << 6) + md * 16 + quad * 4) = o;
        }
}

extern "C" void kernel_launch(void* const* d_in, const int* in_sizes, int n_in,
                              void* d_out, int out_size, void* d_ws, size_t ws_size,
                              hipStream_t stream) {
    (void)in_sizes; (void)n_in; (void)out_size;
    const float* Q = (const float*)d_in[0];
    const float* K = (const float*)d_in[1];
    const float* V = (const float*)d_in[2];
    const void* mask = d_in[4];
    float* O = (float*)d_out;

    const size_t bitfield_bytes = (size_t)S_LEN * S_LEN / 8;       // 2 MB
    const size_t opart_bytes = (size_t)2 * 16 * S_LEN * 64 * 4;    // 33.55 MB
    const size_t lpart_bytes = (size_t)2 * 16 * S_LEN * 4;         // 0.52 MB
    const size_t need_packed = 1024 + bitfield_bytes;
    const size_t need_split = need_packed + opart_bytes + lpart_bytes;

    unsigned long long* pmw = (unsigned long long*)((char*)d_ws + 1024);
    float* opart = (float*)((char*)d_ws + need_packed);
    float* lpart = opart + (size_t)2 * 16 * S_LEN * 64;

    if (d_ws != nullptr && ws_size >= need_split) {
        pack_mask_kernel<<<dim3(16384), 256, 0, stream>>>((const unsigned*)mask, pmw);
        attn_partial<<<dim3(S_LEN / 128, 16, 2), 256, 0, stream>>>(
            Q, K, V, pmw, opart, lpart);
        combine_kernel<<<dim3(16 * S_LEN / 16), 256, 0, stream>>>(opart, lpart, O);
    } else {
        attn_kernel<<<dim3(S_LEN / 128, 16), 256, 0, stream>>>(
            Q, K, V, (const unsigned*)mask, O);
    }
}

// Round 8
// 310.420 us; speedup vs baseline: 1.1999x; 1.1999x over previous
//
#include <hip/hip_runtime.h>
#include <stdint.h>

#define S_LEN 4096
#define SCALE_LOG2E 0.18033688011112042f   // (1/sqrt(64)) * log2(e), folded into Q

typedef __attribute__((ext_vector_type(8))) short bf16x8;
typedef __attribute__((ext_vector_type(4))) float f32x4;

#if __has_builtin(__builtin_amdgcn_exp2f)
#define EXP2(x) __builtin_amdgcn_exp2f(x)
#else
#define EXP2(x) exp2f(x)
#endif

__device__ __forceinline__ unsigned pk2(float a, float b) {
    // round-half-up bf16 pair pack: +0x8000 then take high halves via v_perm
    unsigned ua = __builtin_bit_cast(unsigned, a) + 0x8000u;
    unsigned ub = __builtin_bit_cast(unsigned, b) + 0x8000u;
    return __builtin_amdgcn_perm(ub, ua, 0x07060302u);
}

__device__ __forceinline__ f32x4 mfma16(bf16x8 a, bf16x8 b, f32x4 c) {
    return __builtin_amdgcn_mfma_f32_16x16x32_bf16(a, b, c, 0, 0, 0);
}

// ------------- mask packing: bool(any encoding) -> bitfield, [kt][q] layout --
__global__ void pack_mask_kernel(const unsigned* __restrict__ m32,
                                 unsigned long long* __restrict__ out) {
    const int lane = threadIdx.x & 63;
    const int w = threadIdx.x >> 6;
    unsigned pv = m32[lane];
    bool okw = (pv == 0u) || (pv == 1u) || (pv == 0x3F800000u);
    const bool is_word = (__ballot(okw) == ~0ull);
    const long long wbase = ((long long)blockIdx.x * 4 + w) * 4;   // u64 words (q*64+kt)
    const unsigned char* m8 = (const unsigned char*)m32;
#pragma unroll
    for (int it = 0; it < 4; ++it) {
        const long long word = wbase + it;
        long long e = word * 64 + lane;
        bool bit = is_word ? (m32[e] != 0u) : (m8[e] != 0);
        unsigned long long bal = __ballot(bit);
        if (lane == 0) {
            long long q = word >> 6, kt = word & 63;
            out[kt * S_LEN + q] = bal;   // transposed: coalesced reads in attn
        }
    }
}

// ---------------- staging: global fp32 -> regs (packed bf16), 256 threads ----
__device__ __forceinline__ void pf_load(const float* __restrict__ K,
                                        const float* __restrict__ V,
                                        int bh, int k0, int t,
                                        unsigned* kb, unsigned* vb) {
    const int r = t >> 2, h = t & 3;
    const float* kp = K + (((size_t)(bh * S_LEN + k0 + r)) << 6) + h * 16;
#pragma unroll
    for (int cc = 0; cc < 2; ++cc) {
        float4 f0 = ((const float4*)kp)[cc * 2];
        float4 f1 = ((const float4*)kp)[cc * 2 + 1];
        kb[cc * 4 + 0] = pk2(f0.x, f0.y);
        kb[cc * 4 + 1] = pk2(f0.z, f0.w);
        kb[cc * 4 + 2] = pk2(f1.x, f1.y);
        kb[cc * 4 + 3] = pk2(f1.z, f1.w);
    }
    const int d = t & 63, g = t >> 6;
    const float* vp = V + (((size_t)(bh * S_LEN + k0 + g * 16)) << 6) + d;
#pragma unroll
    for (int c8 = 0; c8 < 2; ++c8) {
        float f[8];
#pragma unroll
        for (int i = 0; i < 8; ++i) f[i] = vp[(c8 * 8 + i) * 64];
        vb[c8 * 4 + 0] = pk2(f[0], f[1]);
        vb[c8 * 4 + 1] = pk2(f[2], f[3]);
        vb[c8 * 4 + 2] = pk2(f[4], f[5]);
        vb[c8 * 4 + 3] = pk2(f[6], f[7]);
    }
}

__device__ __forceinline__ void pf_store(int t, const unsigned* kb, const unsigned* vb,
                                         unsigned short* lk, unsigned short* lv) {
    const int r = t >> 2, h = t & 3;
#pragma unroll
    for (int cc = 0; cc < 2; ++cc) {
        int c = h * 2 + cc;
        uint4 st = {kb[cc * 4 + 0], kb[cc * 4 + 1], kb[cc * 4 + 2], kb[cc * 4 + 3]};
        *(uint4*)&lk[r * 64 + ((c ^ (r & 7)) << 3)] = st;
    }
    const int d = t & 63, g = t >> 6;
#pragma unroll
    for (int c8 = 0; c8 < 2; ++c8) {
        int c = g * 2 + c8;
        uint4 st = {vb[c8 * 4 + 0], vb[c8 * 4 + 1], vb[c8 * 4 + 2], vb[c8 * 4 + 3]};
        *(uint4*)&lv[d * 64 + ((c ^ (d & 7)) << 3)] = st;
    }
}

// ---------------- one 64-key tile: S^T = K·Q^T, softmax, O^T += V^T·P^T ------
// wave q-tile = 32 rows (nt in {0,1}); Q pre-scaled by scale*log2e.
// P transposed C-layout -> B-operand layout via per-wave private LDS (lp,
// 32 rows x 128 B = 4 KB per wave), no barrier (same-wave lgkm ordering).
__device__ __forceinline__ void compute_tile(
    int kt, int q0w, int n16, int quad,
    const unsigned long long (&mrow)[2],
    const unsigned* __restrict__ rawmask,
    int use_packed, int mask_is_word,
    const unsigned short* lk, const unsigned short* lv, unsigned short* lp,
    const bf16x8 (&aq)[2][2], f32x4 (&oacc)[4][2], float (&lsum)[2]) {
    const int k0 = kt * 64;
    // S^T[k'][q] : A = K rows (m = k'), B = Q rows (n = q)
    f32x4 sac[4][2];
    const f32x4 z = {0.f, 0.f, 0.f, 0.f};
#pragma unroll
    for (int mt = 0; mt < 4; ++mt)
#pragma unroll
        for (int nt = 0; nt < 2; ++nt) sac[mt][nt] = z;
#pragma unroll
    for (int kd = 0; kd < 2; ++kd) {
#pragma unroll
        for (int mt = 0; mt < 4; ++mt) {
            int row = mt * 16 + n16;
            bf16x8 ak = *(const bf16x8*)&lk[row * 64 + (((kd * 4 + quad) ^ (row & 7)) << 3)];
#pragma unroll
            for (int nt = 0; nt < 2; ++nt)
                sac[mt][nt] = mfma16(ak, aq[nt][kd], sac[mt][nt]);
        }
    }
    // softmax numerators; write P pairs to lp rows [q:32][k':64] (128 B rows)
#pragma unroll
    for (int mt = 0; mt < 4; ++mt) {
#pragma unroll
        for (int nt = 0; nt < 2; ++nt) {
            float p[4];
#pragma unroll
            for (int reg = 0; reg < 4; ++reg) {
                float e = EXP2(sac[mt][nt][reg]);
                int pos = mt * 16 + quad * 4 + reg;
                bool bit;
                if (use_packed) {
                    bit = (mrow[nt] >> pos) & 1ull;
                } else {
                    size_t mi = (size_t)(q0w + nt * 16 + n16) * S_LEN + k0 + pos;
                    bit = mask_is_word ? (rawmask[mi] != 0u)
                                       : (((const unsigned char*)rawmask)[mi] != 0);
                }
                p[reg] = bit ? e : 0.0f;
            }
            lsum[nt] += (p[0] + p[1]) + (p[2] + p[3]);
            uint2 pr = {pk2(p[0], p[1]), pk2(p[2], p[3])};
            const int r = nt * 16 + n16;
            const int chunk = (mt * 2 + (quad >> 1)) ^ (n16 & 7);
            *(uint2*)((char*)lp + r * 128 + chunk * 16 + (quad & 1) * 8) = pr;
        }
    }
    // O^T[d][q] += V^T · P^T ; P^T B-fragments read back from lp
#pragma unroll
    for (int kk = 0; kk < 2; ++kk) {
        bf16x8 av[4];
#pragma unroll
        for (int md = 0; md < 4; ++md) {
            int dr = md * 16 + n16;
            av[md] = *(const bf16x8*)&lv[dr * 64 + (((kk * 4 + quad) ^ (dr & 7)) << 3)];
        }
#pragma unroll
        for (int nt = 0; nt < 2; ++nt) {
            const int r = nt * 16 + n16;
            const int chunk = (kk * 4 + quad) ^ (n16 & 7);
            bf16x8 pb = *(const bf16x8*)((const char*)lp + r * 128 + chunk * 16);
#pragma unroll
            for (int md = 0; md < 4; ++md)
                oacc[md][nt] = mfma16(av[md], pb, oacc[md][nt]);
        }
    }
}

__device__ __forceinline__ void load_q_frags(const float* __restrict__ Q, int bh, int q0w,
                                             int n16, int quad, bf16x8 (&aq)[2][2]) {
#pragma unroll
    for (int nt = 0; nt < 2; ++nt) {
        const float* qp = Q + ((size_t)(bh * S_LEN + q0w + nt * 16 + n16) << 6);
#pragma unroll
        for (int kd = 0; kd < 2; ++kd) {
            float4 f0 = *(const float4*)(qp + kd * 32 + quad * 8);
            float4 f1 = *(const float4*)(qp + kd * 32 + quad * 8 + 4);
            uint4 u = {pk2(f0.x * SCALE_LOG2E, f0.y * SCALE_LOG2E),
                       pk2(f0.z * SCALE_LOG2E, f0.w * SCALE_LOG2E),
                       pk2(f1.x * SCALE_LOG2E, f1.y * SCALE_LOG2E),
                       pk2(f1.z * SCALE_LOG2E, f1.w * SCALE_LOG2E)};
            aq[nt][kd] = __builtin_bit_cast(bf16x8, u);
        }
    }
}

// ============ K-split partial kernel: blockIdx.z = key half, packed mask =====
// Single-buffered LDS staging (2 barriers/tile): kb/vb are short-lived temps,
// cutting the live register set below the 3-waves/EU threshold (~170).
// Cross-block co-scheduling (3 blocks/CU) covers the staging stall.
__global__ __launch_bounds__(256, 3) void attn_partial(
    const float* __restrict__ Q, const float* __restrict__ K, const float* __restrict__ V,
    const unsigned long long* __restrict__ pm,
    float* __restrict__ Opart, float* __restrict__ Lpart) {
    __shared__ __align__(16) unsigned short lk[64 * 64];
    __shared__ __align__(16) unsigned short lv[64 * 64];
    __shared__ __align__(16) unsigned short lpbuf[4][32 * 64];   // 4 KB per wave
    const int tid = threadIdx.x;
    const int lane = tid & 63;
    const int w = tid >> 6;
    const int n16 = lane & 15;
    const int quad = lane >> 4;
    const int bh = blockIdx.y;
    const int half = blockIdx.z;
    const int q0w = blockIdx.x * 128 + w * 32;
    const int kbase = half * 2048;
    unsigned short* lp = lpbuf[w];

    bf16x8 aq[2][2];
    load_q_frags(Q, bh, q0w, n16, quad, aq);

    f32x4 oacc[4][2];
    const f32x4 z = {0.f, 0.f, 0.f, 0.f};
#pragma unroll
    for (int md = 0; md < 4; ++md)
#pragma unroll
        for (int nt = 0; nt < 2; ++nt) oacc[md][nt] = z;
    float lsum[2] = {0.f, 0.f};

    for (int ktl = 0; ktl < 32; ++ktl) {
        __syncthreads();   // previous compute done; safe to overwrite lk/lv
        {
            unsigned kb[8], vb[8];
            pf_load(K, V, bh, kbase + ktl * 64, tid, kb, vb);
            pf_store(tid, kb, vb, lk, lv);
        }
        unsigned long long mrow[2];
#pragma unroll
        for (int nt = 0; nt < 2; ++nt)
            mrow[nt] = pm[(size_t)(half * 32 + ktl) * S_LEN + q0w + nt * 16 + n16];
        __syncthreads();   // staging visible
        compute_tile(half * 32 + ktl, q0w, n16, quad, mrow, nullptr, 1, 1,
                     lk, lv, lp, aq, oacc, lsum);
    }

    // store raw partial O^T (no normalization) + reduced row sums
#pragma unroll
    for (int nt = 0; nt < 2; ++nt) {
        float l = lsum[nt];
        l += __shfl_xor(l, 16);
        l += __shfl_xor(l, 32);
        int q = q0w + nt * 16 + n16;
        if (quad == 0) Lpart[((size_t)(half * 16 + bh) << 12) + q] = l;
#pragma unroll
        for (int md = 0; md < 4; ++md) {
            float4 o;
            o.x = oacc[md][nt][0];
            o.y = oacc[md][nt][1];
            o.z = oacc[md][nt][2];
            o.w = oacc[md][nt][3];
            *(float4*)(Opart + (((size_t)(half * 16 + bh) << 12) + q) * 64 +
                       md * 16 + quad * 4) = o;
        }
    }
}

// ============ combine: O = (O0 + O1) / (l0 + l1) =============================
__global__ __launch_bounds__(256) void combine_kernel(
    const float* __restrict__ Opart, const float* __restrict__ Lpart,
    float* __restrict__ O) {
    const int row = blockIdx.x * 16 + (threadIdx.x >> 4);      // bh*4096+q
    const int d4 = (threadIdx.x & 15) * 4;
    const float* p0 = Opart + (size_t)row * 64 + d4;
    const float* p1 = p0 + (size_t)16 * S_LEN * 64;
    float4 a = *(const float4*)p0;
    float4 b = *(const float4*)p1;
    float l = Lpart[row] + Lpart[16 * S_LEN + row];
    float r = (l > 0.f) ? (1.0f / l) : 0.0f;
    float4 o;
    o.x = (a.x + b.x) * r;
    o.y = (a.y + b.y) * r;
    o.z = (a.z + b.z) * r;
    o.w = (a.w + b.w) * r;
    *(float4*)(O + (size_t)row * 64 + d4) = o;
}

// ============ fallback: single kernel, full key range, raw mask ==============
__global__ __launch_bounds__(256, 3) void attn_kernel(
    const float* __restrict__ Q, const float* __restrict__ K, const float* __restrict__ V,
    const unsigned* __restrict__ rawmask, float* __restrict__ O) {
    __shared__ __align__(16) unsigned short lk[64 * 64];
    __shared__ __align__(16) unsigned short lv[64 * 64];
    __shared__ __align__(16) unsigned short lpbuf[4][32 * 64];   // 4 KB per wave
    const int tid = threadIdx.x;
    const int lane = tid & 63;
    const int w = tid >> 6;
    const int n16 = lane & 15;
    const int quad = lane >> 4;
    const int bh = blockIdx.y;
    const int q0w = blockIdx.x * 128 + w * 32;
    unsigned short* lp = lpbuf[w];

    unsigned v = rawmask[lane];
    bool okw = (v == 0u) || (v == 1u) || (v == 0x3F800000u);
    const int mask_is_word = (__ballot(okw) == ~0ull) ? 1 : 0;

    bf16x8 aq[2][2];
    load_q_frags(Q, bh, q0w, n16, quad, aq);

    f32x4 oacc[4][2];
    const f32x4 z = {0.f, 0.f, 0.f, 0.f};
#pragma unroll
    for (int md = 0; md < 4; ++md)
#pragma unroll
        for (int nt = 0; nt < 2; ++nt) oacc[md][nt] = z;
    float lsum[2] = {0.f, 0.f};

    for (int kt = 0; kt < 64; ++kt) {
        __syncthreads();
        {
            unsigned kb[8], vb[8];
            pf_load(K, V, bh, kt * 64, tid, kb, vb);
            pf_store(tid, kb, vb, lk, lv);
        }
        unsigned long long mrow[2] = {0, 0};   // unused on raw path
        __syncthreads();
        compute_tile(kt, q0w, n16, quad, mrow, rawmask, 0, mask_is_word,
                     lk, lv, lp, aq, oacc, lsum);
    }

    float rcpl[2];
#pragma unroll
    for (int nt = 0; nt < 2; ++nt) {
        float l = lsum[nt];
        l += __shfl_xor(l, 16);
        l += __shfl_xor(l, 32);
        rcpl[nt] = (l > 0.f) ? (1.0f / l) : 0.0f;
    }
#pragma unroll
    for (int md = 0; md < 4; ++md)
#pragma unroll
        for (int nt = 0; nt < 2; ++nt) {
            int q = q0w + nt * 16 + n16;
            float4 o;
            o.x = oacc[md][nt][0] * rcpl[nt];
            o.y = oacc[md][nt][1] * rcpl[nt];
            o.z = oacc[md][nt][2] * rcpl[nt];
            o.w = oacc[md][nt][3] * rcpl[nt];
            *(float4*)(O + ((size_t)(bh * S_LEN + q) << 6) + md * 16 + quad * 4) = o;
        }
}

extern "C" void kernel_launch(void* const* d_in, const int* in_sizes, int n_in,
                              void* d_out, int out_size, void* d_ws, size_t ws_size,
                              hipStream_t stream) {
    (void)in_sizes; (void)n_in; (void)out_size;
    const float* Q = (const float*)d_in[0];
    const float* K = (const float*)d_in[1];
    const float* V = (const float*)d_in[2];
    const void* mask = d_in[4];
    float* O = (float*)d_out;

    const size_t bitfield_bytes = (size_t)S_LEN * S_LEN / 8;       // 2 MB
    const size_t opart_bytes = (size_t)2 * 16 * S_LEN * 64 * 4;    // 33.55 MB
    const size_t lpart_bytes = (size_t)2 * 16 * S_LEN * 4;         // 0.52 MB
    const size_t need_packed = 1024 + bitfield_bytes;
    const size_t need_split = need_packed + opart_bytes + lpart_bytes;

    unsigned long long* pmw = (unsigned long long*)((char*)d_ws + 1024);
    float* opart = (float*)((char*)d_ws + need_packed);
    float* lpart = opart + (size_t)2 * 16 * S_LEN * 64;

    if (d_ws != nullptr && ws_size >= need_split) {
        pack_mask_kernel<<<dim3(16384), 256, 0, stream>>>((const unsigned*)mask, pmw);
        attn_partial<<<dim3(S_LEN / 128, 16, 2), 256, 0, stream>>>(
            Q, K, V, pmw, opart, lpart);
        combine_kernel<<<dim3(16 * S_LEN / 16), 256, 0, stream>>>(opart, lpart, O);
    } else {
        attn_kernel<<<dim3(S_LEN / 128, 16), 256, 0, stream>>>(
            Q, K, V, (const unsigned*)mask, O);
    }
}

// Round 10
// 303.620 us; speedup vs baseline: 1.2268x; 1.0224x over previous
//
#include <hip/hip_runtime.h>
#include <stdint.h>

#define S_LEN 4096
#define SCALE_LOG2E 0.18033688011112042f   // (1/sqrt(64)) * log2(e), folded into Q

typedef __attribute__((ext_vector_type(8))) short bf16x8;
typedef __attribute__((ext_vector_type(4))) float f32x4;

#if __has_builtin(__builtin_amdgcn_exp2f)
#define EXP2(x) __builtin_amdgcn_exp2f(x)
#else
#define EXP2(x) exp2f(x)
#endif

__device__ __forceinline__ unsigned pk2(float a, float b) {
    // round-half-up bf16 pair pack: +0x8000 then take high halves via v_perm
    unsigned ua = __builtin_bit_cast(unsigned, a) + 0x8000u;
    unsigned ub = __builtin_bit_cast(unsigned, b) + 0x8000u;
    return __builtin_amdgcn_perm(ub, ua, 0x07060302u);
}

__device__ __forceinline__ f32x4 mfma16(bf16x8 a, bf16x8 b, f32x4 c) {
    return __builtin_amdgcn_mfma_f32_16x16x32_bf16(a, b, c, 0, 0, 0);
}

// ------------- mask packing: bool(any encoding) -> bitfield, [kt][q] layout --
__global__ void pack_mask_kernel(const unsigned* __restrict__ m32,
                                 unsigned long long* __restrict__ out) {
    const int lane = threadIdx.x & 63;
    const int w = threadIdx.x >> 6;
    unsigned pv = m32[lane];
    bool okw = (pv == 0u) || (pv == 1u) || (pv == 0x3F800000u);
    const bool is_word = (__ballot(okw) == ~0ull);
    const long long wbase = ((long long)blockIdx.x * 4 + w) * 4;   // u64 words (q*64+kt)
    const unsigned char* m8 = (const unsigned char*)m32;
#pragma unroll
    for (int it = 0; it < 4; ++it) {
        const long long word = wbase + it;
        long long e = word * 64 + lane;
        bool bit = is_word ? (m32[e] != 0u) : (m8[e] != 0);
        unsigned long long bal = __ballot(bit);
        if (lane == 0) {
            long long q = word >> 6, kt = word & 63;
            out[kt * S_LEN + q] = bal;   // transposed: coalesced reads in attn
        }
    }
}

// ---------------- staging: global fp32 -> regs (packed bf16), 256 threads ----
__device__ __forceinline__ void pf_load(const float* __restrict__ K,
                                        const float* __restrict__ V,
                                        int bh, int k0, int t,
                                        unsigned* kb, unsigned* vb) {
    const int r = t >> 2, h = t & 3;
    const float* kp = K + (((size_t)(bh * S_LEN + k0 + r)) << 6) + h * 16;
#pragma unroll
    for (int cc = 0; cc < 2; ++cc) {
        float4 f0 = ((const float4*)kp)[cc * 2];
        float4 f1 = ((const float4*)kp)[cc * 2 + 1];
        kb[cc * 4 + 0] = pk2(f0.x, f0.y);
        kb[cc * 4 + 1] = pk2(f0.z, f0.w);
        kb[cc * 4 + 2] = pk2(f1.x, f1.y);
        kb[cc * 4 + 3] = pk2(f1.z, f1.w);
    }
    const int d = t & 63, g = t >> 6;
    const float* vp = V + (((size_t)(bh * S_LEN + k0 + g * 16)) << 6) + d;
#pragma unroll
    for (int c8 = 0; c8 < 2; ++c8) {
        float f[8];
#pragma unroll
        for (int i = 0; i < 8; ++i) f[i] = vp[(c8 * 8 + i) * 64];
        vb[c8 * 4 + 0] = pk2(f[0], f[1]);
        vb[c8 * 4 + 1] = pk2(f[2], f[3]);
        vb[c8 * 4 + 2] = pk2(f[4], f[5]);
        vb[c8 * 4 + 3] = pk2(f[6], f[7]);
    }
}

__device__ __forceinline__ void pf_store(int t, const unsigned* kb, const unsigned* vb,
                                         unsigned short* lk, unsigned short* lv) {
    const int r = t >> 2, h = t & 3;
#pragma unroll
    for (int cc = 0; cc < 2; ++cc) {
        int c = h * 2 + cc;
        uint4 st = {kb[cc * 4 + 0], kb[cc * 4 + 1], kb[cc * 4 + 2], kb[cc * 4 + 3]};
        *(uint4*)&lk[r * 64 + ((c ^ (r & 7)) << 3)] = st;
    }
    const int d = t & 63, g = t >> 6;
#pragma unroll
    for (int c8 = 0; c8 < 2; ++c8) {
        int c = g * 2 + c8;
        uint4 st = {vb[c8 * 4 + 0], vb[c8 * 4 + 1], vb[c8 * 4 + 2], vb[c8 * 4 + 3]};
        *(uint4*)&lv[d * 64 + ((c ^ (d & 7)) << 3)] = st;
    }
}

// ---------------- one 64-key tile: S^T = K·Q^T, softmax, O^T += V^T·P^T ------
// wave q-tile = 32 rows (nt in {0,1}); Q pre-scaled by scale*log2e.
// QK^T done in two 32-key passes (mth) so sac is [2][2] (16 regs live, not 32)
// — targets the 3-waves/EU unified-register threshold. lp keeps R5's proven
// 128-B-row layout (all 32 banks, ~2-way only). PV runs after both passes.
__device__ __forceinline__ void compute_tile(
    int kt, int q0w, int n16, int quad,
    const unsigned long long (&mrow)[2],
    const unsigned* __restrict__ rawmask,
    int use_packed, int mask_is_word,
    const unsigned short* lk, const unsigned short* lv, unsigned short* lp,
    const bf16x8 (&aq)[2][2], f32x4 (&oacc)[4][2], float (&lsum)[2]) {
    const int k0 = kt * 64;
    const f32x4 z = {0.f, 0.f, 0.f, 0.f};
#pragma unroll
    for (int mth = 0; mth < 2; ++mth) {
        // S^T[k'][q] for k' in [mth*32, mth*32+32)
        f32x4 sac[2][2];
#pragma unroll
        for (int mi = 0; mi < 2; ++mi)
#pragma unroll
            for (int nt = 0; nt < 2; ++nt) sac[mi][nt] = z;
#pragma unroll
        for (int kd = 0; kd < 2; ++kd) {
#pragma unroll
            for (int mi = 0; mi < 2; ++mi) {
                int row = (mth * 2 + mi) * 16 + n16;
                bf16x8 ak = *(const bf16x8*)&lk[row * 64 + (((kd * 4 + quad) ^ (row & 7)) << 3)];
#pragma unroll
                for (int nt = 0; nt < 2; ++nt)
                    sac[mi][nt] = mfma16(ak, aq[nt][kd], sac[mi][nt]);
            }
        }
        // softmax numerators; write P pairs to lp rows [q:32][k':64] (128 B rows)
#pragma unroll
        for (int mi = 0; mi < 2; ++mi) {
#pragma unroll
            for (int nt = 0; nt < 2; ++nt) {
                const int mt = mth * 2 + mi;
                float p[4];
#pragma unroll
                for (int reg = 0; reg < 4; ++reg) {
                    float e = EXP2(sac[mi][nt][reg]);
                    int pos = mt * 16 + quad * 4 + reg;
                    bool bit;
                    if (use_packed) {
                        bit = (mrow[nt] >> pos) & 1ull;
                    } else {
                        size_t mi2 = (size_t)(q0w + nt * 16 + n16) * S_LEN + k0 + pos;
                        bit = mask_is_word ? (rawmask[mi2] != 0u)
                                           : (((const unsigned char*)rawmask)[mi2] != 0);
                    }
                    p[reg] = bit ? e : 0.0f;
                }
                lsum[nt] += (p[0] + p[1]) + (p[2] + p[3]);
                uint2 pr = {pk2(p[0], p[1]), pk2(p[2], p[3])};
                const int r = nt * 16 + n16;
                const int chunk = (mt * 2 + (quad >> 1)) ^ (n16 & 7);
                *(uint2*)((char*)lp + r * 128 + chunk * 16 + (quad & 1) * 8) = pr;
            }
        }
    }
    // O^T[d][q] += V^T · P^T ; P^T B-fragments read back from lp
#pragma unroll
    for (int kk = 0; kk < 2; ++kk) {
        bf16x8 av[4];
#pragma unroll
        for (int md = 0; md < 4; ++md) {
            int dr = md * 16 + n16;
            av[md] = *(const bf16x8*)&lv[dr * 64 + (((kk * 4 + quad) ^ (dr & 7)) << 3)];
        }
#pragma unroll
        for (int nt = 0; nt < 2; ++nt) {
            const int r = nt * 16 + n16;
            const int chunk = (kk * 4 + quad) ^ (n16 & 7);
            bf16x8 pb = *(const bf16x8*)((const char*)lp + r * 128 + chunk * 16);
#pragma unroll
            for (int md = 0; md < 4; ++md)
                oacc[md][nt] = mfma16(av[md], pb, oacc[md][nt]);
        }
    }
}

__device__ __forceinline__ void load_q_frags(const float* __restrict__ Q, int bh, int q0w,
                                             int n16, int quad, bf16x8 (&aq)[2][2]) {
#pragma unroll
    for (int nt = 0; nt < 2; ++nt) {
        const float* qp = Q + ((size_t)(bh * S_LEN + q0w + nt * 16 + n16) << 6);
#pragma unroll
        for (int kd = 0; kd < 2; ++kd) {
            float4 f0 = *(const float4*)(qp + kd * 32 + quad * 8);
            float4 f1 = *(const float4*)(qp + kd * 32 + quad * 8 + 4);
            uint4 u = {pk2(f0.x * SCALE_LOG2E, f0.y * SCALE_LOG2E),
                       pk2(f0.z * SCALE_LOG2E, f0.w * SCALE_LOG2E),
                       pk2(f1.x * SCALE_LOG2E, f1.y * SCALE_LOG2E),
                       pk2(f1.z * SCALE_LOG2E, f1.w * SCALE_LOG2E)};
            aq[nt][kd] = __builtin_bit_cast(bf16x8, u);
        }
    }
}

// ============ K-split partial kernel: blockIdx.z = key half, packed mask =====
__global__ __launch_bounds__(256, 3) void attn_partial(
    const float* __restrict__ Q, const float* __restrict__ K, const float* __restrict__ V,
    const unsigned long long* __restrict__ pm,
    float* __restrict__ Opart, float* __restrict__ Lpart) {
    __shared__ __align__(16) unsigned short lk[2][64 * 64];
    __shared__ __align__(16) unsigned short lv[2][64 * 64];
    __shared__ __align__(16) unsigned short lpbuf[4][32 * 64];   // 4 KB per wave
    const int tid = threadIdx.x;
    const int lane = tid & 63;
    const int w = tid >> 6;
    const int n16 = lane & 15;
    const int quad = lane >> 4;
    const int bh = blockIdx.y;
    const int half = blockIdx.z;
    const int q0w = blockIdx.x * 128 + w * 32;
    const int kbase = half * 2048;
    unsigned short* lp = lpbuf[w];

    bf16x8 aq[2][2];
    load_q_frags(Q, bh, q0w, n16, quad, aq);

    f32x4 oacc[4][2];
    const f32x4 z = {0.f, 0.f, 0.f, 0.f};
#pragma unroll
    for (int md = 0; md < 4; ++md)
#pragma unroll
        for (int nt = 0; nt < 2; ++nt) oacc[md][nt] = z;
    float lsum[2] = {0.f, 0.f};

    unsigned kb[8], vb[8];
    pf_load(K, V, bh, kbase, tid, kb, vb);
    pf_store(tid, kb, vb, lk[0], lv[0]);
    unsigned long long mrow_cur[2], mrow_nxt[2];
#pragma unroll
    for (int nt = 0; nt < 2; ++nt)
        mrow_cur[nt] = pm[(size_t)(half * 32) * S_LEN + q0w + nt * 16 + n16];

    for (int ktl = 0; ktl < 32; ++ktl) {
        const int cur = ktl & 1;
        const int ktn = (ktl + 1) & 31;
        __syncthreads();
        pf_load(K, V, bh, kbase + ktn * 64, tid, kb, vb);
#pragma unroll
        for (int nt = 0; nt < 2; ++nt)
            mrow_nxt[nt] = pm[(size_t)(half * 32 + ktn) * S_LEN + q0w + nt * 16 + n16];
        compute_tile(half * 32 + ktl, q0w, n16, quad, mrow_cur, nullptr, 1, 1,
                     cur ? lk[1] : lk[0], cur ? lv[1] : lv[0], lp, aq, oacc, lsum);
        pf_store(tid, kb, vb, cur ? lk[0] : lk[1], cur ? lv[0] : lv[1]);
        mrow_cur[0] = mrow_nxt[0];
        mrow_cur[1] = mrow_nxt[1];
    }

    // store raw partial O^T (no normalization) + reduced row sums
#pragma unroll
    for (int nt = 0; nt < 2; ++nt) {
        float l = lsum[nt];
        l += __shfl_xor(l, 16);
        l += __shfl_xor(l, 32);
        int q = q0w + nt * 16 + n16;
        if (quad == 0) Lpart[((size_t)(half * 16 + bh) << 12) + q] = l;
#pragma unroll
        for (int md = 0; md < 4; ++md) {
            float4 o;
            o.x = oacc[md][nt][0];
            o.y = oacc[md][nt][1];
            o.z = oacc[md][nt][2];
            o.w = oacc[md][nt][3];
            *(float4*)(Opart + (((size_t)(half * 16 + bh) << 12) + q) * 64 +
                       md * 16 + quad * 4) = o;
        }
    }
}

// ============ combine: O = (O0 + O1) / (l0 + l1) =============================
__global__ __launch_bounds__(256) void combine_kernel(
    const float* __restrict__ Opart, const float* __restrict__ Lpart,
    float* __restrict__ O) {
    const int row = blockIdx.x * 16 + (threadIdx.x >> 4);      // bh*4096+q
    const int d4 = (threadIdx.x & 15) * 4;
    const float* p0 = Opart + (size_t)row * 64 + d4;
    const float* p1 = p0 + (size_t)16 * S_LEN * 64;
    float4 a = *(const float4*)p0;
    float4 b = *(const float4*)p1;
    float l = Lpart[row] + Lpart[16 * S_LEN + row];
    float r = (l > 0.f) ? (1.0f / l) : 0.0f;
    float4 o;
    o.x = (a.x + b.x) * r;
    o.y = (a.y + b.y) * r;
    o.z = (a.z + b.z) * r;
    o.w = (a.w + b.w) * r;
    *(float4*)(O + (size_t)row * 64 + d4) = o;
}

// ============ fallback: single kernel, full key range ========================
__global__ __launch_bounds__(256, 3) void attn_kernel(
    const float* __restrict__ Q, const float* __restrict__ K, const float* __restrict__ V,
    const unsigned long long* __restrict__ pm, const unsigned* __restrict__ rawmask,
    int use_packed, float* __restrict__ O) {
    __shared__ __align__(16) unsigned short lk[2][64 * 64];
    __shared__ __align__(16) unsigned short lv[2][64 * 64];
    __shared__ __align__(16) unsigned short lpbuf[4][32 * 64];
    const int tid = threadIdx.x;
    const int lane = tid & 63;
    const int w = tid >> 6;
    const int n16 = lane & 15;
    const int quad = lane >> 4;
    const int bh = blockIdx.y;
    const int q0w = blockIdx.x * 128 + w * 32;
    unsigned short* lp = lpbuf[w];

    int mask_is_word = 1;
    if (!use_packed) {
        unsigned v = rawmask[lane];
        bool okw = (v == 0u) || (v == 1u) || (v == 0x3F800000u);
        mask_is_word = (__ballot(okw) == ~0ull) ? 1 : 0;
    }

    bf16x8 aq[2][2];
    load_q_frags(Q, bh, q0w, n16, quad, aq);

    f32x4 oacc[4][2];
    const f32x4 z = {0.f, 0.f, 0.f, 0.f};
#pragma unroll
    for (int md = 0; md < 4; ++md)
#pragma unroll
        for (int nt = 0; nt < 2; ++nt) oacc[md][nt] = z;
    float lsum[2] = {0.f, 0.f};

    unsigned kb[8], vb[8];
    pf_load(K, V, bh, 0, tid, kb, vb);
    pf_store(tid, kb, vb, lk[0], lv[0]);
    unsigned long long mrow_cur[2] = {0, 0}, mrow_nxt[2] = {0, 0};
    if (use_packed) {
#pragma unroll
        for (int nt = 0; nt < 2; ++nt)
            mrow_cur[nt] = pm[(size_t)0 * S_LEN + q0w + nt * 16 + n16];
    }

    for (int kt = 0; kt < 64; ++kt) {
        const int cur = kt & 1;
        const int ktn = (kt + 1) & 63;
        __syncthreads();
        pf_load(K, V, bh, ktn * 64, tid, kb, vb);
        if (use_packed) {
#pragma unroll
            for (int nt = 0; nt < 2; ++nt)
                mrow_nxt[nt] = pm[(size_t)ktn * S_LEN + q0w + nt * 16 + n16];
        }
        compute_tile(kt, q0w, n16, quad, mrow_cur, rawmask, use_packed, mask_is_word,
                     cur ? lk[1] : lk[0], cur ? lv[1] : lv[0], lp, aq, oacc, lsum);
        pf_store(tid, kb, vb, cur ? lk[0] : lk[1], cur ? lv[0] : lv[1]);
        mrow_cur[0] = mrow_nxt[0];
        mrow_cur[1] = mrow_nxt[1];
    }

    float rcpl[2];
#pragma unroll
    for (int nt = 0; nt < 2; ++nt) {
        float l = lsum[nt];
        l += __shfl_xor(l, 16);
        l += __shfl_xor(l, 32);
        rcpl[nt] = (l > 0.f) ? (1.0f / l) : 0.0f;
    }
#pragma unroll
    for (int md = 0; md < 4; ++md)
#pragma unroll
        for (int nt = 0; nt < 2; ++nt) {
            int q = q0w + nt * 16 + n16;
            float4 o;
            o.x = oacc[md][nt][0] * rcpl[nt];
            o.y = oacc[md][nt][1] * rcpl[nt];
            o.z = oacc[md][nt][2] * rcpl[nt];
            o.w = oacc[md][nt][3] * rcpl[nt];
            *(float4*)(O + ((size_t)(bh * S_LEN + q) << 6) + md * 16 + quad * 4) = o;
        }
}

extern "C" void kernel_launch(void* const* d_in, const int* in_sizes, int n_in,
                              void* d_out, int out_size, void* d_ws, size_t ws_size,
                              hipStream_t stream) {
    (void)in_sizes; (void)n_in; (void)out_size;
    const float* Q = (const float*)d_in[0];
    const float* K = (const float*)d_in[1];
    const float* V = (const float*)d_in[2];
    const void* mask = d_in[4];
    float* O = (float*)d_out;

    const size_t bitfield_bytes = (size_t)S_LEN * S_LEN / 8;       // 2 MB
    const size_t opart_bytes = (size_t)2 * 16 * S_LEN * 64 * 4;    // 33.55 MB
    const size_t lpart_bytes = (size_t)2 * 16 * S_LEN * 4;         // 0.52 MB
    const size_t need_packed = 1024 + bitfield_bytes;
    const size_t need_split = need_packed + opart_bytes + lpart_bytes;

    unsigned long long* pmw = (unsigned long long*)((char*)d_ws + 1024);
    float* opart = (float*)((char*)d_ws + need_packed);
    float* lpart = opart + (size_t)2 * 16 * S_LEN * 64;

    if (d_ws != nullptr && ws_size >= need_split) {
        pack_mask_kernel<<<dim3(16384), 256, 0, stream>>>((const unsigned*)mask, pmw);
        attn_partial<<<dim3(S_LEN / 128, 16, 2), 256, 0, stream>>>(
            Q, K, V, pmw, opart, lpart);
        combine_kernel<<<dim3(16 * S_LEN / 16), 256, 0, stream>>>(opart, lpart, O);
    } else if (d_ws != nullptr && ws_size >= need_packed) {
        pack_mask_kernel<<<dim3(16384), 256, 0, stream>>>((const unsigned*)mask, pmw);
        attn_kernel<<<dim3(S_LEN / 128, 16), 256, 0, stream>>>(
            Q, K, V, pmw, (const unsigned*)mask, 1, O);
    } else {
        attn_kernel<<<dim3(S_LEN / 128, 16), 256, 0, stream>>>(
            Q, K, V, nullptr, (const unsigned*)mask, 0, O);
    }
}